// Round 11
// baseline (2138.828 us; speedup 1.0000x reference)
//
#include <hip/hip_runtime.h>
#include <stdint.h>

// ============================================================================
// DIAGNOSTIC ROUND: template<MODE> ablation of the proven R5 kernel (205 us).
// MODE 0 = full kernel (writes d_out, exact R5 semantics, x3 repeat)
// MODE 1 = -STAGE : no per-iter global loads / LDS writes (compute on tile 0)
// MODE 2 = -MASK  : no mask loads/packing (mask bits = 0)
// MODE 3 = -PV    : no PV ds_reads + MFMAs (pw kept live via asm sink)
// MODE 4 = -SM    : no exp2/mask/cvtpk chain (pw <- mov(sacc), psum <- sacc)
// All x3-repeated so each dispatch exceeds the ~320us fillBuffer dispatches
// and appears in the rocprof top-5 table. Modes 1-4 write to d_ws only.
// ============================================================================

#define NB    32
#define SLQ   2048
#define SLK   2048
#define DD    128
#define QTILE 128          // q rows per workgroup (4 waves x 32)
#define KVB   64           // keys per block iteration
#define NKB   (SLK / KVB)  // 32
#define NREP  3            // repeat factor for profiler visibility

typedef __attribute__((ext_vector_type(8)))  short    bf16x8;
typedef __attribute__((ext_vector_type(16))) float    f32x16;
typedef __attribute__((ext_vector_type(4)))  float    f32x4v;
typedef __attribute__((ext_vector_type(4)))  uint32_t u32x4;
typedef __attribute__((ext_vector_type(2)))  uint32_t u32x2;

union FragU { uint32_t u[4]; bf16x8 v; };

__device__ __forceinline__ uint32_t cvtpk(float lo, float hi) {
    uint32_t r;
    asm("v_cvt_pk_bf16_f32 %0, %1, %2" : "=v"(r) : "v"(lo), "v"(hi));
    return r;
}
__device__ __forceinline__ void perm32swap(uint32_t& a, uint32_t& b) {
    asm("v_permlane32_swap_b32 %0, %1" : "+v"(a), "+v"(b));
}
__device__ __forceinline__ uint32_t pack16(u32x4 a) {
    uint32_t r0 = (((a.x & 0x01010101u) * 0x01020408u) >> 24) & 0xFu;
    uint32_t r1 = (((a.y & 0x01010101u) * 0x01020408u) >> 24) & 0xFu;
    uint32_t r2 = (((a.z & 0x01010101u) * 0x01020408u) >> 24) & 0xFu;
    uint32_t r3 = (((a.w & 0x01010101u) * 0x01020408u) >> 24) & 0xFu;
    return r0 | (r1 << 4) | (r2 << 8) | (r3 << 12);
}
#if __has_builtin(__builtin_amdgcn_exp2f)
#define EXP2(x) __builtin_amdgcn_exp2f(x)
#else
#define EXP2(x) exp2f(x)
#endif

template <int MODE>
__global__ __launch_bounds__(256, 2)
void attn_abl(const float* __restrict__ qp, const float* __restrict__ kp,
              const float* __restrict__ vp, const void* __restrict__ mp,
              float* __restrict__ outp)
{
    __shared__ short    k_lds[KVB * DD];    // [64 key][128 d] bf16, 16B-XOR swizzle
    __shared__ short    vt_lds[DD * KVB];   // [128 d][64 key] bf16, 8B-XOR swizzle
    __shared__ uint32_t m_lds[QTILE * 2];   // [128 q][2] dwords of key-bits
    __shared__ int      det_flags;

    const int tid  = threadIdx.x;
    const int lane = tid & 63;
    const int wv   = tid >> 6;
    const int l31  = lane & 31;
    const int hi2  = lane >> 5;

    const int bid = blockIdx.x;
    const int wg  = (bid & 7) * 64 + (bid >> 3);
    const int b   = wg >> 4;
    const int q0  = (wg & 15) * QTILE;

    if (tid == 0) det_flags = 0;
    __syncthreads();
    {
        const u32x4 w = *(const u32x4*)((const char*)mp + tid * 16);
        const uint32_t any_hi    = (w.x | w.y | w.z | w.w) & 0xFFFFFF00u;
        const uint32_t any_mod84 = (w.y | w.w) & 0xFFu;
        const int f = (any_hi ? 1 : 0) | (any_mod84 ? 2 : 0);
        if (f) atomicOr(&det_flags, f);
    }
    __syncthreads();
    const int mflags = det_flags;
    const int mmode  = (mflags & 1) ? 0 : ((mflags & 2) ? 1 : 2);

    const float qsc = 0.12751744846458246f;  // log2(e)/sqrt(128)

    bf16x8 qf[8];
    {
        const float* qrow = qp + ((size_t)b * SLQ + (size_t)(q0 + wv * 32 + l31)) * DD;
        #pragma unroll
        for (int ks = 0; ks < 8; ++ks) {
            f32x4v x0 = *(const f32x4v*)(qrow + 16 * ks + 8 * hi2);
            f32x4v x1 = *(const f32x4v*)(qrow + 16 * ks + 8 * hi2 + 4);
            FragU f;
            f.u[0] = cvtpk(x0.x * qsc, x0.y * qsc);
            f.u[1] = cvtpk(x0.z * qsc, x0.w * qsc);
            f.u[2] = cvtpk(x1.x * qsc, x1.y * qsc);
            f.u[3] = cvtpk(x1.z * qsc, x1.w * qsc);
            qf[ks] = f.v;
        }
    }

    const float* kb0 = kp + (size_t)b * SLK * DD;
    const float* vb0 = vp + (size_t)b * SLK * DD;
    const size_t mrow0 = ((size_t)b * SLQ + q0) * SLK;

    f32x4v kreg[8];
    float  vreg[32];
    u32x4  mreg[2];

    const int vd  = tid & 127;
    const int vkh = tid >> 7;
    const int mqq = tid >> 1;
    const int mh  = tid & 1;
    const int swv = (vd & 15) << 3;

    #define LOAD_TILE(KB)                                                         \
        do {                                                                      \
            const int k0_ = (KB) * KVB;                                           \
            const float* kbase_ = kb0 + (size_t)k0_ * DD;                         \
            _Pragma("unroll")                                                     \
            for (int j = 0; j < 8; ++j)                                           \
                kreg[j] = *(const f32x4v*)(kbase_ + (j * 256 + tid) * 4);         \
            const float* vcol_ = vb0 + ((size_t)k0_ + 32 * vkh) * DD + vd;        \
            _Pragma("unroll")                                                     \
            for (int jj = 0; jj < 32; ++jj) vreg[jj] = vcol_[(size_t)jj * DD];    \
            if constexpr (MODE != 2) {                                            \
                if (mmode == 0) {                                                 \
                    const uint8_t* ms_ = (const uint8_t*)mp + mrow0 +             \
                                         (size_t)mqq * SLK + k0_ + mh * 32;       \
                    mreg[0] = *(const u32x4*)(ms_);                               \
                    mreg[1] = *(const u32x4*)(ms_ + 16);                          \
                }                                                                 \
            }                                                                     \
        } while (0)

    #define WRITE_LDS(KB)                                                         \
        do {                                                                      \
            _Pragma("unroll")                                                     \
            for (int j = 0; j < 8; ++j) {                                         \
                const int flat = (j * 256 + tid) * 4;                             \
                const int kk   = flat >> 7;                                       \
                const int dd2  = (flat & 127) * 2;                                \
                u32x2 w2;                                                         \
                w2.x = cvtpk(kreg[j].x, kreg[j].y);                               \
                w2.y = cvtpk(kreg[j].z, kreg[j].w);                               \
                *(u32x2*)((char*)k_lds + kk * 256 + (dd2 ^ ((kk & 7) << 4))) = w2;\
            }                                                                     \
            {                                                                     \
                char* vrow_ = (char*)vt_lds + vd * 128;                           \
                _Pragma("unroll")                                                 \
                for (int j = 0; j < 8; ++j) {                                     \
                    u32x2 w2;                                                     \
                    w2.x = cvtpk(vreg[4 * j + 0], vreg[4 * j + 1]);               \
                    w2.y = cvtpk(vreg[4 * j + 2], vreg[4 * j + 3]);               \
                    *(u32x2*)(vrow_ + ((vkh * 64 + 8 * j) ^ swv)) = w2;           \
                }                                                                 \
            }                                                                     \
            if constexpr (MODE != 2) {                                            \
                if (mmode == 0) {                                                 \
                    m_lds[mqq * 2 + mh] =                                         \
                        pack16(mreg[0]) | (pack16(mreg[1]) << 16);                \
                } else {                                                          \
                    const size_t e0_ = mrow0 + (size_t)mqq * SLK + (KB) * KVB + mh * 32; \
                    uint32_t bits = 0;                                            \
                    if (mmode == 1) {                                             \
                        const uint32_t* s_ = (const uint32_t*)mp + e0_;           \
                        for (int j = 0; j < 32; ++j) bits |= (s_[j] ? 1u : 0u) << j; \
                    } else {                                                      \
                        const uint64_t* s_ = (const uint64_t*)mp + e0_;           \
                        for (int j = 0; j < 32; ++j) bits |= (s_[j] ? 1u : 0u) << j; \
                    }                                                             \
                    m_lds[mqq * 2 + mh] = bits;                                   \
                }                                                                 \
            }                                                                     \
        } while (0)

    f32x16 oacc[4];
    float  psum;

    for (int rep = 0; rep < NREP; ++rep) {
        #pragma unroll
        for (int i = 0; i < 4; ++i)
            #pragma unroll
            for (int j = 0; j < 16; ++j) oacc[i][j] = 0.0f;
        psum = 0.0f;

        LOAD_TILE(0);

        for (int kb = 0; kb < NKB; ++kb) {
            // ---- stage phase (ablated in MODE 1 after tile 0) ----
            if constexpr (MODE == 1) {
                if (kb == 0) WRITE_LDS(0);
            } else {
                WRITE_LDS(kb);
            }
            __syncthreads();

            if constexpr (MODE != 1) {
                if (kb + 1 < NKB) LOAD_TILE(kb + 1);
            }
            __builtin_amdgcn_sched_barrier(0);

            // ---- swapped QK^T ----
            f32x16 sacc[2];
            #pragma unroll
            for (int t = 0; t < 2; ++t)
                #pragma unroll
                for (int j = 0; j < 16; ++j) sacc[t][j] = 0.0f;
            __builtin_amdgcn_s_setprio(1);
            #pragma unroll
            for (int t = 0; t < 2; ++t) {
                const int row = 32 * t + l31;
                const char* krow = (const char*)k_lds + row * 256;
                const int sw = (row & 7) << 4;
                #pragma unroll
                for (int ks = 0; ks < 8; ++ks) {
                    bf16x8 af = *(const bf16x8*)(krow + ((32 * ks + 16 * hi2) ^ sw));
                    sacc[t] = __builtin_amdgcn_mfma_f32_32x32x16_bf16(af, qf[ks], sacc[t], 0, 0, 0);
                }
            }
            __builtin_amdgcn_s_setprio(0);

            // ---- softmax (ablated in MODE 4) ----
            uint32_t pw[2][8];
            if constexpr (MODE == 4) {
                #pragma unroll
                for (int t = 0; t < 2; ++t) {
                    #pragma unroll
                    for (int rr = 0; rr < 4; ++rr) {
                        asm volatile("v_mov_b32 %0, %1"
                                     : "=v"(pw[t][2 * rr]) : "v"(sacc[t][4 * rr]));
                        asm volatile("v_mov_b32 %0, %1"
                                     : "=v"(pw[t][2 * rr + 1]) : "v"(sacc[t][4 * rr + 2]));
                        psum += sacc[t][4 * rr];
                    }
                }
            } else {
                u32x2 mq;
                if constexpr (MODE == 2) { mq.x = 0u; mq.y = 0u; }
                else mq = *(const u32x2*)(&m_lds[(32 * wv + l31) * 2]);
                #pragma unroll
                for (int t = 0; t < 2; ++t) {
                    #pragma unroll
                    for (int rr = 0; rr < 4; ++rr) {
                        const uint32_t mn = ((t ? mq.y : mq.x) >> (8 * rr + 4 * hi2)) & 0xFu;
                        float em[4];
                        #pragma unroll
                        for (int c = 0; c < 4; ++c) {
                            const float e = EXP2(sacc[t][4 * rr + c]);
                            em[c] = ((mn >> c) & 1u) ? 0.0f : e;
                        }
                        psum += (em[0] + em[1]) + (em[2] + em[3]);
                        pw[t][2 * rr]     = cvtpk(em[0], em[1]);
                        pw[t][2 * rr + 1] = cvtpk(em[2], em[3]);
                    }
                }
            }

            // ---- PV (ablated in MODE 3; pw kept live via asm sink) ----
            if constexpr (MODE == 3) {
                #pragma unroll
                for (int t = 0; t < 2; ++t)
                    asm volatile("" :: "v"(pw[t][0]), "v"(pw[t][1]), "v"(pw[t][2]),
                                       "v"(pw[t][3]), "v"(pw[t][4]), "v"(pw[t][5]),
                                       "v"(pw[t][6]), "v"(pw[t][7]));
            } else {
                #pragma unroll
                for (int t = 0; t < 2; ++t) {
                    #pragma unroll
                    for (int kss = 0; kss < 2; ++kss) {
                        uint32_t a0 = pw[t][4 * kss + 0], b0 = pw[t][4 * kss + 2];
                        uint32_t a1 = pw[t][4 * kss + 1], b1 = pw[t][4 * kss + 3];
                        perm32swap(a0, b0);
                        perm32swap(a1, b1);
                        FragU af;
                        af.u[0] = a0; af.u[1] = a1; af.u[2] = b0; af.u[3] = b1;
                        const int keyb = 64 * t + 32 * kss + 16 * hi2;
                        __builtin_amdgcn_s_setprio(1);
                        #pragma unroll
                        for (int dt = 0; dt < 4; ++dt) {
                            const int drow = 32 * dt + l31;
                            const char* vrow = (const char*)vt_lds + drow * 128;
                            const int sw8 = (drow & 15) << 3;
                            FragU vf;
                            *(u32x2*)&vf.u[0] = *(const u32x2*)(vrow + ((keyb)     ^ sw8));
                            *(u32x2*)&vf.u[2] = *(const u32x2*)(vrow + ((keyb + 8) ^ sw8));
                            oacc[dt] = __builtin_amdgcn_mfma_f32_32x32x16_bf16(af.v, vf.v, oacc[dt], 0, 0, 0);
                        }
                        __builtin_amdgcn_s_setprio(0);
                    }
                }
            }
            __syncthreads();
        }
    }

    // ---- epilogue (last rep's state; identical math to R5 for MODE 0) ----
    psum += __shfl_xor(psum, 32);
    float* obase = outp + ((size_t)b * SLQ + (size_t)(q0 + 32 * wv)) * DD + l31;
    #pragma unroll
    for (int r = 0; r < 16; ++r) {
        const int qrow = (r & 3) + 8 * (r >> 2) + 4 * hi2;
        const float s  = __shfl(psum, qrow);
        const float rs = 1.0f / s;
        #pragma unroll
        for (int dt = 0; dt < 4; ++dt) {
            obase[(size_t)qrow * DD + 32 * dt] = oacc[dt][r] * rs;
        }
    }
}

extern "C" void kernel_launch(void* const* d_in, const int* in_sizes, int n_in,
                              void* d_out, int out_size, void* d_ws, size_t ws_size,
                              hipStream_t stream)
{
    const float* q = (const float*)d_in[0];
    const float* k = (const float*)d_in[1];
    const float* v = (const float*)d_in[2];
    const void*  m = d_in[3];
    float*       o = (float*)d_out;
    float*       w = (float*)d_ws;

    const size_t ovol = (size_t)NB * SLQ * DD;
    const dim3 grid((NB * SLQ) / QTILE), blk(256);

    // Ablation dispatches (write d_ws), then the real kernel (writes d_out).
    if (ws_size >= 4 * ovol * sizeof(float)) {
        hipLaunchKernelGGL((attn_abl<1>), grid, blk, 0, stream, q, k, v, m, w + 0 * ovol);
        hipLaunchKernelGGL((attn_abl<2>), grid, blk, 0, stream, q, k, v, m, w + 1 * ovol);
        hipLaunchKernelGGL((attn_abl<3>), grid, blk, 0, stream, q, k, v, m, w + 2 * ovol);
        hipLaunchKernelGGL((attn_abl<4>), grid, blk, 0, stream, q, k, v, m, w + 3 * ovol);
    }
    hipLaunchKernelGGL((attn_abl<0>), grid, blk, 0, stream, q, k, v, m, o);
}

// Round 12
// 426.285 us; speedup vs baseline: 5.0174x; 5.0174x over previous
//
#include <hip/hip_runtime.h>
#include <stdint.h>

// Problem constants (B, LQ, LK, D fixed by the reference)
#define NB    32
#define SLQ   2048
#define SLK   2048
#define DD    128
#define QTILE 256          // q rows per workgroup (8 waves x 32)
#define KVB   128          // keys per block iteration (R12: 2x R5)
#define NKB   (SLK / KVB)  // 16

typedef __attribute__((ext_vector_type(8)))  short    bf16x8;
typedef __attribute__((ext_vector_type(16))) float    f32x16;
typedef __attribute__((ext_vector_type(4)))  float    f32x4v;
typedef __attribute__((ext_vector_type(4)))  uint32_t u32x4;
typedef __attribute__((ext_vector_type(2)))  uint32_t u32x2;

union FragU { uint32_t u[4]; bf16x8 v; };

// HW packed f32->bf16 (RNE), 1 inst per pair
__device__ __forceinline__ uint32_t cvtpk(float lo, float hi) {
    uint32_t r;
    asm("v_cvt_pk_bf16_f32 %0, %1, %2" : "=v"(r) : "v"(lo), "v"(hi));
    return r;
}
// a' = {lanes<32: a, lanes>=32: b[lane-32]}; b' = {lanes<32: a[lane+32], lanes>=32: b}
__device__ __forceinline__ void perm32swap(uint32_t& a, uint32_t& b) {
    asm("v_permlane32_swap_b32 %0, %1" : "+v"(a), "+v"(b));
}
// 16 mask bytes (0/1) -> 16 bits
__device__ __forceinline__ uint32_t pack16(u32x4 a) {
    uint32_t r0 = (((a.x & 0x01010101u) * 0x01020408u) >> 24) & 0xFu;
    uint32_t r1 = (((a.y & 0x01010101u) * 0x01020408u) >> 24) & 0xFu;
    uint32_t r2 = (((a.z & 0x01010101u) * 0x01020408u) >> 24) & 0xFu;
    uint32_t r3 = (((a.w & 0x01010101u) * 0x01020408u) >> 24) & 0xFu;
    return r0 | (r1 << 4) | (r2 << 8) | (r3 << 12);
}
#if __has_builtin(__builtin_amdgcn_exp2f)
#define EXP2(x) __builtin_amdgcn_exp2f(x)
#else
#define EXP2(x) exp2f(x)
#endif

__global__ __launch_bounds__(512, 2)
void attn_fwd(const float* __restrict__ qp, const float* __restrict__ kp,
              const float* __restrict__ vp, const void* __restrict__ mp,
              float* __restrict__ op)
{
    // 32K K + 32K V^T + 4K mask bits = 68KB (gfx950 LDS/CU = 160KB)
    __shared__ short    k_lds[KVB * DD];     // [128 key][128 d] bf16, rows 256B, 16B-XOR
    __shared__ short    vt_lds[DD * KVB];    // [128 d][128 key] bf16, rows 256B, 8B-XOR
    __shared__ uint32_t m_lds[QTILE * 4];    // [256 q][4] dwords of key-bits
    __shared__ int      det_flags;

    const int tid  = threadIdx.x;
    const int lane = tid & 63;
    const int wv   = tid >> 6;   // wave 0..7, owns q rows [q0+32*wv, +32)
    const int l31  = lane & 31;
    const int hi2  = lane >> 5;  // 0/1

    // XCD-chunked swizzle: 256 WGs, 8 XCDs -> 32 consecutive work ids each
    const int bid = blockIdx.x;
    const int wg  = (bid & 7) * 32 + (bid >> 3);
    const int b   = wg >> 3;            // batch
    const int q0  = (wg & 7) * QTILE;   // q tile origin

    // ---- mask dtype self-detection (R2 FETCH proved u8; keep as safety) ----
    if (tid == 0) det_flags = 0;
    __syncthreads();
    if (tid < 256) {
        const u32x4 w = *(const u32x4*)((const char*)mp + tid * 16);
        const uint32_t any_hi    = (w.x | w.y | w.z | w.w) & 0xFFFFFF00u;
        const uint32_t any_mod84 = (w.y | w.w) & 0xFFu;
        const int f = (any_hi ? 1 : 0) | (any_mod84 ? 2 : 0);
        if (f) atomicOr(&det_flags, f);
    }
    __syncthreads();
    const int mflags = det_flags;
    const int mmode  = (mflags & 1) ? 0 : ((mflags & 2) ? 1 : 2);  // 0=u8, 1=i32, 2=i64

    // scale = log2(e)/sqrt(128): scores land in log2 units -> softmax is bare v_exp
    const float qsc = 0.12751744846458246f;

    // ---- persistent Q fragments (B-operand of swapped QK^T) ----
    bf16x8 qf[8];
    {
        const float* qrow = qp + ((size_t)b * SLQ + (size_t)(q0 + wv * 32 + l31)) * DD;
        #pragma unroll
        for (int ks = 0; ks < 8; ++ks) {
            f32x4v x0 = *(const f32x4v*)(qrow + 16 * ks + 8 * hi2);
            f32x4v x1 = *(const f32x4v*)(qrow + 16 * ks + 8 * hi2 + 4);
            FragU f;
            f.u[0] = cvtpk(x0.x * qsc, x0.y * qsc);
            f.u[1] = cvtpk(x0.z * qsc, x0.w * qsc);
            f.u[2] = cvtpk(x1.x * qsc, x1.y * qsc);
            f.u[3] = cvtpk(x1.z * qsc, x1.w * qsc);
            qf[ks] = f.v;
        }
    }

    f32x16 oacc[4];
    #pragma unroll
    for (int i = 0; i < 4; ++i)
        #pragma unroll
        for (int j = 0; j < 16; ++j) oacc[i][j] = 0.0f;
    float psum = 0.0f;

    const float* kb0 = kp + (size_t)b * SLK * DD;
    const float* vb0 = vp + (size_t)b * SLK * DD;
    const size_t mrow0 = ((size_t)b * SLQ + q0) * SLK;

    // ---- prefetch registers (T14), split across 512 threads ----
    f32x4v kreg[8];   // 128x128 f32 / 512 thr = 8 x 16B
    float  vreg[32];  // 32 key-rows of this thread's d column
    u32x4  mreg[4];   // 64 mask bytes

    const int vd  = tid & 127;       // d-row this thread stages for V^T
    const int vkh = tid >> 7;        // 0..3 -> keys 32*vkh .. +31
    const int mqq = tid >> 1;        // mask q row (0..255)
    const int mh  = tid & 1;         // mask 64-key half
    const int swv = (vd & 31) << 3;  // V^T 8B-granular XOR over 256B rows

    #define LOAD_TILE(KB)                                                         \
        do {                                                                      \
            const int k0_ = (KB) * KVB;                                           \
            const float* kbase_ = kb0 + (size_t)k0_ * DD;                         \
            _Pragma("unroll")                                                     \
            for (int j = 0; j < 8; ++j)                                           \
                kreg[j] = *(const f32x4v*)(kbase_ + (j * 512 + tid) * 4);         \
            const float* vcol_ = vb0 + ((size_t)k0_ + 32 * vkh) * DD + vd;        \
            _Pragma("unroll")                                                     \
            for (int jj = 0; jj < 32; ++jj) vreg[jj] = vcol_[(size_t)jj * DD];    \
            if (mmode == 0) {                                                     \
                const uint8_t* ms_ = (const uint8_t*)mp + mrow0 +                 \
                                     (size_t)mqq * SLK + k0_ + mh * 64;           \
                mreg[0] = *(const u32x4*)(ms_);                                   \
                mreg[1] = *(const u32x4*)(ms_ + 16);                              \
                mreg[2] = *(const u32x4*)(ms_ + 32);                              \
                mreg[3] = *(const u32x4*)(ms_ + 48);                              \
            }                                                                     \
        } while (0)

    #define WRITE_LDS(KB)                                                         \
        do {                                                                      \
            _Pragma("unroll")                                                     \
            for (int j = 0; j < 8; ++j) {                                         \
                const int flat = (j * 512 + tid) * 4;                             \
                const int kk   = flat >> 7;          /* key row 0..127 */         \
                const int dd2  = (flat & 127) * 2;                                \
                u32x2 w2;                                                         \
                w2.x = cvtpk(kreg[j].x, kreg[j].y);                               \
                w2.y = cvtpk(kreg[j].z, kreg[j].w);                               \
                *(u32x2*)((char*)k_lds + kk * 256 + (dd2 ^ ((kk & 7) << 4))) = w2;\
            }                                                                     \
            {                                                                     \
                char* vrow_ = (char*)vt_lds + vd * 256;                           \
                _Pragma("unroll")                                                 \
                for (int j = 0; j < 8; ++j) {                                     \
                    u32x2 w2;                                                     \
                    w2.x = cvtpk(vreg[4 * j + 0], vreg[4 * j + 1]);               \
                    w2.y = cvtpk(vreg[4 * j + 2], vreg[4 * j + 3]);               \
                    *(u32x2*)(vrow_ + ((vkh * 64 + 8 * j) ^ swv)) = w2;           \
                }                                                                 \
            }                                                                     \
            if (mmode == 0) {                                                     \
                m_lds[mqq * 4 + 2 * mh]     = pack16(mreg[0]) | (pack16(mreg[1]) << 16); \
                m_lds[mqq * 4 + 2 * mh + 1] = pack16(mreg[2]) | (pack16(mreg[3]) << 16); \
            } else {                                                              \
                const size_t e0_ = mrow0 + (size_t)mqq * SLK + (KB) * KVB + mh * 64; \
                uint32_t b0_ = 0, b1_ = 0;                                        \
                if (mmode == 1) {                                                 \
                    const uint32_t* s_ = (const uint32_t*)mp + e0_;               \
                    for (int j = 0; j < 32; ++j) b0_ |= (s_[j] ? 1u : 0u) << j;   \
                    for (int j = 0; j < 32; ++j) b1_ |= (s_[32 + j] ? 1u : 0u) << j; \
                } else {                                                          \
                    const uint64_t* s_ = (const uint64_t*)mp + e0_;               \
                    for (int j = 0; j < 32; ++j) b0_ |= (s_[j] ? 1u : 0u) << j;   \
                    for (int j = 0; j < 32; ++j) b1_ |= (s_[32 + j] ? 1u : 0u) << j; \
                }                                                                 \
                m_lds[mqq * 4 + 2 * mh]     = b0_;                                \
                m_lds[mqq * 4 + 2 * mh + 1] = b1_;                                \
            }                                                                     \
        } while (0)

    LOAD_TILE(0);

    for (int kb = 0; kb < NKB; ++kb) {
        // ---- write LDS from prefetch regs; vmcnt waits land here, covered by
        //      the (now 2x longer) previous compute phase ----
        WRITE_LDS(kb);
        __syncthreads();

        // ---- issue next tile's loads, pinned above compute ----
        if (kb + 1 < NKB) LOAD_TILE(kb + 1);
        __builtin_amdgcn_sched_barrier(0);

        // mask bits for this lane's q-row (q = 32wv + l31), 128 keys
        const u32x4 mq = *(const u32x4*)(&m_lds[(32 * wv + l31) * 4]);

        // ---- 4 x { swapped QK^T(32 keys) -> softmax -> pack } interleaved ----
        uint32_t pw[4][8];
        #pragma unroll
        for (int t = 0; t < 4; ++t) {
            const int row = 32 * t + l31;
            const char* krow = (const char*)k_lds + row * 256;
            const int sw = (row & 7) << 4;
            f32x16 sacc;
            #pragma unroll
            for (int j = 0; j < 16; ++j) sacc[j] = 0.0f;
            __builtin_amdgcn_s_setprio(1);
            #pragma unroll
            for (int ks = 0; ks < 8; ++ks) {
                bf16x8 af = *(const bf16x8*)(krow + ((32 * ks + 16 * hi2) ^ sw));
                sacc = __builtin_amdgcn_mfma_f32_32x32x16_bf16(af, qf[ks], sacc, 0, 0, 0);
            }
            __builtin_amdgcn_s_setprio(0);
            const uint32_t mword = (t & 2) ? ((t & 1) ? mq.w : mq.z)
                                           : ((t & 1) ? mq.y : mq.x);
            #pragma unroll
            for (int rr = 0; rr < 4; ++rr) {
                const uint32_t mn = (mword >> (8 * rr + 4 * hi2)) & 0xFu;
                float em[4];
                #pragma unroll
                for (int c = 0; c < 4; ++c) {
                    const float e = EXP2(sacc[4 * rr + c]);
                    em[c] = ((mn >> c) & 1u) ? 0.0f : e;
                }
                psum += (em[0] + em[1]) + (em[2] + em[3]);
                pw[t][2 * rr]     = cvtpk(em[0], em[1]);
                pw[t][2 * rr + 1] = cvtpk(em[2], em[3]);
            }
        }

        // ---- PV: O[32q x 128d] += P[32x128] * V[128x128] ----
        #pragma unroll
        for (int t = 0; t < 4; ++t) {
            #pragma unroll
            for (int kss = 0; kss < 2; ++kss) {
                uint32_t a0 = pw[t][4 * kss + 0], b0 = pw[t][4 * kss + 2];
                uint32_t a1 = pw[t][4 * kss + 1], b1 = pw[t][4 * kss + 3];
                perm32swap(a0, b0);
                perm32swap(a1, b1);
                FragU af;
                af.u[0] = a0; af.u[1] = a1; af.u[2] = b0; af.u[3] = b1;
                const int keyb = 64 * t + 32 * kss + 16 * hi2;  // byte offset in 256B row
                __builtin_amdgcn_s_setprio(1);
                #pragma unroll
                for (int dt = 0; dt < 4; ++dt) {
                    const int drow = 32 * dt + l31;
                    const char* vrow = (const char*)vt_lds + drow * 256;
                    const int sw8 = (drow & 31) << 3;
                    FragU vf;
                    *(u32x2*)&vf.u[0] = *(const u32x2*)(vrow + ((keyb)     ^ sw8));
                    *(u32x2*)&vf.u[2] = *(const u32x2*)(vrow + ((keyb + 8) ^ sw8));
                    oacc[dt] = __builtin_amdgcn_mfma_f32_32x32x16_bf16(af.v, vf.v, oacc[dt], 0, 0, 0);
                }
                __builtin_amdgcn_s_setprio(0);
            }
        }
        __syncthreads();
    }

    // ---- epilogue: combine halves of row-sums, normalize, store fp32 ----
    psum += __shfl_xor(psum, 32);
    float* obase = op + ((size_t)b * SLQ + (size_t)(q0 + 32 * wv)) * DD + l31;
    #pragma unroll
    for (int r = 0; r < 16; ++r) {
        const int qrow = (r & 3) + 8 * (r >> 2) + 4 * hi2;
        const float s  = __shfl(psum, qrow);
        const float rs = 1.0f / s;
        #pragma unroll
        for (int dt = 0; dt < 4; ++dt) {
            obase[(size_t)qrow * DD + 32 * dt] = oacc[dt][r] * rs;
        }
    }
}

extern "C" void kernel_launch(void* const* d_in, const int* in_sizes, int n_in,
                              void* d_out, int out_size, void* d_ws, size_t ws_size,
                              hipStream_t stream)
{
    const float* q = (const float*)d_in[0];
    const float* k = (const float*)d_in[1];
    const float* v = (const float*)d_in[2];
    const void*  m = d_in[3];
    float*       o = (float*)d_out;
    hipLaunchKernelGGL(attn_fwd, dim3((NB * SLQ) / QTILE), dim3(512), 0, stream,
                       q, k, v, m, o);
}

// Round 13
// 345.219 us; speedup vs baseline: 6.1956x; 1.2348x over previous
//
#include <hip/hip_runtime.h>
#include <stdint.h>

// Problem constants (B, LQ, LK, D fixed by the reference)
#define NB    32
#define SLQ   2048
#define SLK   2048
#define DD    128
#define QTILE 256          // q rows per workgroup (8 waves x 32)
#define KVB   128          // keys per block iteration
#define NKB   (SLK / KVB)  // 16

typedef __attribute__((ext_vector_type(8)))  short    bf16x8;
typedef __attribute__((ext_vector_type(16))) float    f32x16;
typedef __attribute__((ext_vector_type(4)))  float    f32x4v;
typedef __attribute__((ext_vector_type(4)))  uint32_t u32x4;
typedef __attribute__((ext_vector_type(2)))  uint32_t u32x2;

union FragU { uint32_t u[4]; bf16x8 v; };

// HW packed f32->bf16 (RNE), 1 inst per pair
__device__ __forceinline__ uint32_t cvtpk(float lo, float hi) {
    uint32_t r;
    asm("v_cvt_pk_bf16_f32 %0, %1, %2" : "=v"(r) : "v"(lo), "v"(hi));
    return r;
}
// a' = {lanes<32: a, lanes>=32: b[lane-32]}; b' = {lanes<32: a[lane+32], lanes>=32: b}
__device__ __forceinline__ void perm32swap(uint32_t& a, uint32_t& b) {
    asm("v_permlane32_swap_b32 %0, %1" : "+v"(a), "+v"(b));
}
// 16 mask bytes (0/1) -> 16 bits
__device__ __forceinline__ uint32_t pack16(u32x4 a) {
    uint32_t r0 = (((a.x & 0x01010101u) * 0x01020408u) >> 24) & 0xFu;
    uint32_t r1 = (((a.y & 0x01010101u) * 0x01020408u) >> 24) & 0xFu;
    uint32_t r2 = (((a.z & 0x01010101u) * 0x01020408u) >> 24) & 0xFu;
    uint32_t r3 = (((a.w & 0x01010101u) * 0x01020408u) >> 24) & 0xFu;
    return r0 | (r1 << 4) | (r2 << 8) | (r3 << 12);
}
#if __has_builtin(__builtin_amdgcn_exp2f)
#define EXP2(x) __builtin_amdgcn_exp2f(x)
#else
#define EXP2(x) exp2f(x)
#endif

__global__ __launch_bounds__(512, 2)
void attn_fwd(const float* __restrict__ qp, const float* __restrict__ kp,
              const float* __restrict__ vp, const void* __restrict__ mp,
              float* __restrict__ op)
{
    // 32K K + 32K V^T + 4K mask bits = 68KB (gfx950 LDS/CU = 160KB)
    __shared__ short    k_lds[KVB * DD];     // [128 key][128 d] bf16, rows 256B, 16B-XOR
    __shared__ short    vt_lds[DD * KVB];    // [128 d][128 key] bf16, rows 256B, 8B-XOR
    __shared__ uint32_t m_lds[QTILE * 4];    // [256 q][4] dwords of key-bits
    __shared__ int      det_flags;

    const int tid  = threadIdx.x;
    const int lane = tid & 63;
    const int wv   = tid >> 6;   // wave 0..7, owns q rows [q0+32*wv, +32)
    const int l31  = lane & 31;
    const int hi2  = lane >> 5;  // 0/1

    // XCD-chunked swizzle: 256 WGs, 8 XCDs -> 32 consecutive work ids each
    const int bid = blockIdx.x;
    const int wg  = (bid & 7) * 32 + (bid >> 3);
    const int b   = wg >> 3;            // batch
    const int q0  = (wg & 7) * QTILE;   // q tile origin

    // ---- mask dtype self-detection (R2 FETCH proved u8; keep as safety) ----
    if (tid == 0) det_flags = 0;
    __syncthreads();
    if (tid < 256) {
        const u32x4 w = *(const u32x4*)((const char*)mp + tid * 16);
        const uint32_t any_hi    = (w.x | w.y | w.z | w.w) & 0xFFFFFF00u;
        const uint32_t any_mod84 = (w.y | w.w) & 0xFFu;
        const int f = (any_hi ? 1 : 0) | (any_mod84 ? 2 : 0);
        if (f) atomicOr(&det_flags, f);
    }
    __syncthreads();
    const int mflags = det_flags;
    const int mmode  = (mflags & 1) ? 0 : ((mflags & 2) ? 1 : 2);  // 0=u8, 1=i32, 2=i64

    // scale = log2(e)/sqrt(128): scores land in log2 units -> softmax is bare v_exp
    const float qsc = 0.12751744846458246f;

    // ---- persistent Q fragments (B-operand of swapped QK^T) ----
    bf16x8 qf[8];
    {
        const float* qrow = qp + ((size_t)b * SLQ + (size_t)(q0 + wv * 32 + l31)) * DD;
        #pragma unroll
        for (int ks = 0; ks < 8; ++ks) {
            f32x4v x0 = *(const f32x4v*)(qrow + 16 * ks + 8 * hi2);
            f32x4v x1 = *(const f32x4v*)(qrow + 16 * ks + 8 * hi2 + 4);
            FragU f;
            f.u[0] = cvtpk(x0.x * qsc, x0.y * qsc);
            f.u[1] = cvtpk(x0.z * qsc, x0.w * qsc);
            f.u[2] = cvtpk(x1.x * qsc, x1.y * qsc);
            f.u[3] = cvtpk(x1.z * qsc, x1.w * qsc);
            qf[ks] = f.v;
        }
    }

    f32x16 oacc[4];
    #pragma unroll
    for (int i = 0; i < 4; ++i)
        #pragma unroll
        for (int j = 0; j < 16; ++j) oacc[i][j] = 0.0f;
    float psum = 0.0f;

    const float* kb0 = kp + (size_t)b * SLK * DD;
    const float* vb0 = vp + (size_t)b * SLK * DD;
    const size_t mrow0 = ((size_t)b * SLQ + q0) * SLK;

    // ---- prefetch registers (T14), split across 512 threads ----
    f32x4v kreg[8];   // 128x128 f32 / 512 thr = 8 x 16B
    float  vreg[32];  // 32 key-rows of this thread's d column
    u32x4  mreg[4];   // 64 mask bytes

    const int vd  = tid & 127;       // d-row this thread stages for V^T
    const int vkh = tid >> 7;        // 0..3 -> keys 32*vkh .. +31
    const int mqq = tid >> 1;        // mask q row (0..255)
    const int mh  = tid & 1;         // mask 64-key half
    const int swv = (vd & 31) << 3;  // V^T 8B-granular XOR over 256B rows

    #define LOAD_TILE(KB)                                                         \
        do {                                                                      \
            const int k0_ = (KB) * KVB;                                           \
            const float* kbase_ = kb0 + (size_t)k0_ * DD;                         \
            _Pragma("unroll")                                                     \
            for (int j = 0; j < 8; ++j)                                           \
                kreg[j] = *(const f32x4v*)(kbase_ + (j * 512 + tid) * 4);         \
            const float* vcol_ = vb0 + ((size_t)k0_ + 32 * vkh) * DD + vd;        \
            _Pragma("unroll")                                                     \
            for (int jj = 0; jj < 32; ++jj) vreg[jj] = vcol_[(size_t)jj * DD];    \
            if (mmode == 0) {                                                     \
                const uint8_t* ms_ = (const uint8_t*)mp + mrow0 +                 \
                                     (size_t)mqq * SLK + k0_ + mh * 64;           \
                mreg[0] = *(const u32x4*)(ms_);                                   \
                mreg[1] = *(const u32x4*)(ms_ + 16);                              \
                mreg[2] = *(const u32x4*)(ms_ + 32);                              \
                mreg[3] = *(const u32x4*)(ms_ + 48);                              \
            }                                                                     \
        } while (0)

    #define WRITE_LDS(KB)                                                         \
        do {                                                                      \
            _Pragma("unroll")                                                     \
            for (int j = 0; j < 8; ++j) {                                         \
                const int flat = (j * 512 + tid) * 4;                             \
                const int kk   = flat >> 7;          /* key row 0..127 */         \
                const int dd2  = (flat & 127) * 2;                                \
                u32x2 w2;                                                         \
                w2.x = cvtpk(kreg[j].x, kreg[j].y);                               \
                w2.y = cvtpk(kreg[j].z, kreg[j].w);                               \
                *(u32x2*)((char*)k_lds + kk * 256 + (dd2 ^ ((kk & 7) << 4))) = w2;\
            }                                                                     \
            {                                                                     \
                char* vrow_ = (char*)vt_lds + vd * 256;                           \
                _Pragma("unroll")                                                 \
                for (int j = 0; j < 8; ++j) {                                     \
                    u32x2 w2;                                                     \
                    w2.x = cvtpk(vreg[4 * j + 0], vreg[4 * j + 1]);               \
                    w2.y = cvtpk(vreg[4 * j + 2], vreg[4 * j + 3]);               \
                    *(u32x2*)(vrow_ + ((vkh * 64 + 8 * j) ^ swv)) = w2;           \
                }                                                                 \
            }                                                                     \
            if (mmode == 0) {                                                     \
                m_lds[mqq * 4 + 2 * mh]     = pack16(mreg[0]) | (pack16(mreg[1]) << 16); \
                m_lds[mqq * 4 + 2 * mh + 1] = pack16(mreg[2]) | (pack16(mreg[3]) << 16); \
            } else {                                                              \
                const size_t e0_ = mrow0 + (size_t)mqq * SLK + (KB) * KVB + mh * 64; \
                uint32_t b0_ = 0, b1_ = 0;                                        \
                if (mmode == 1) {                                                 \
                    const uint32_t* s_ = (const uint32_t*)mp + e0_;               \
                    for (int j = 0; j < 32; ++j) b0_ |= (s_[j] ? 1u : 0u) << j;   \
                    for (int j = 0; j < 32; ++j) b1_ |= (s_[32 + j] ? 1u : 0u) << j; \
                } else {                                                          \
                    const uint64_t* s_ = (const uint64_t*)mp + e0_;               \
                    for (int j = 0; j < 32; ++j) b0_ |= (s_[j] ? 1u : 0u) << j;   \
                    for (int j = 0; j < 32; ++j) b1_ |= (s_[32 + j] ? 1u : 0u) << j; \
                }                                                                 \
                m_lds[mqq * 4 + 2 * mh]     = b0_;                                \
                m_lds[mqq * 4 + 2 * mh + 1] = b1_;                                \
            }                                                                     \
        } while (0)

    LOAD_TILE(0);

    for (int kb = 0; kb < NKB; ++kb) {
        // ---- write LDS from prefetch regs; vmcnt waits land here, covered by
        //      the previous (2x longer than R5) compute phase ----
        WRITE_LDS(kb);
        __syncthreads();

        // ---- issue next tile's loads, pinned above compute ----
        if (kb + 1 < NKB) LOAD_TILE(kb + 1);
        __builtin_amdgcn_sched_barrier(0);

        // mask bits for this lane's q-row (q = 32wv + l31), 128 keys
        const u32x4 mq = *(const u32x4*)(&m_lds[(32 * wv + l31) * 4]);

        // ---- 4 x fused { QK^T(32 keys) -> SM -> PV } : one pw live at a time
        //      (R12 held pw[4][8] across all t -> 32-reg spill; this is the fix)
        #pragma unroll
        for (int t = 0; t < 4; ++t) {
            const int row = 32 * t + l31;
            const char* krow = (const char*)k_lds + row * 256;
            const int sw = (row & 7) << 4;
            f32x16 sacc;
            #pragma unroll
            for (int j = 0; j < 16; ++j) sacc[j] = 0.0f;
            __builtin_amdgcn_s_setprio(1);
            #pragma unroll
            for (int ks = 0; ks < 8; ++ks) {
                bf16x8 af = *(const bf16x8*)(krow + ((32 * ks + 16 * hi2) ^ sw));
                sacc = __builtin_amdgcn_mfma_f32_32x32x16_bf16(af, qf[ks], sacc, 0, 0, 0);
            }
            __builtin_amdgcn_s_setprio(0);

            const uint32_t mword = (t & 2) ? ((t & 1) ? mq.w : mq.z)
                                           : ((t & 1) ? mq.y : mq.x);
            uint32_t pw[8];
            #pragma unroll
            for (int rr = 0; rr < 4; ++rr) {
                const uint32_t mn = (mword >> (8 * rr + 4 * hi2)) & 0xFu;
                float em[4];
                #pragma unroll
                for (int c = 0; c < 4; ++c) {
                    const float e = EXP2(sacc[4 * rr + c]);
                    em[c] = ((mn >> c) & 1u) ? 0.0f : e;
                }
                psum += (em[0] + em[1]) + (em[2] + em[3]);
                pw[2 * rr]     = cvtpk(em[0], em[1]);
                pw[2 * rr + 1] = cvtpk(em[2], em[3]);
            }

            #pragma unroll
            for (int kss = 0; kss < 2; ++kss) {
                uint32_t a0 = pw[4 * kss + 0], b0 = pw[4 * kss + 2];
                uint32_t a1 = pw[4 * kss + 1], b1 = pw[4 * kss + 3];
                perm32swap(a0, b0);
                perm32swap(a1, b1);
                FragU af;
                af.u[0] = a0; af.u[1] = a1; af.u[2] = b0; af.u[3] = b1;
                const int keyb = 64 * t + 32 * kss + 16 * hi2;  // byte off in 256B row
                __builtin_amdgcn_s_setprio(1);
                #pragma unroll
                for (int dt = 0; dt < 4; ++dt) {
                    const int drow = 32 * dt + l31;
                    const char* vrow = (const char*)vt_lds + drow * 256;
                    const int sw8 = (drow & 31) << 3;
                    FragU vf;
                    *(u32x2*)&vf.u[0] = *(const u32x2*)(vrow + ((keyb)     ^ sw8));
                    *(u32x2*)&vf.u[2] = *(const u32x2*)(vrow + ((keyb + 8) ^ sw8));
                    oacc[dt] = __builtin_amdgcn_mfma_f32_32x32x16_bf16(af.v, vf.v, oacc[dt], 0, 0, 0);
                }
                __builtin_amdgcn_s_setprio(0);
            }
        }
        __syncthreads();
    }

    // ---- epilogue: combine halves of row-sums, normalize, store fp32 ----
    psum += __shfl_xor(psum, 32);
    float* obase = op + ((size_t)b * SLQ + (size_t)(q0 + 32 * wv)) * DD + l31;
    #pragma unroll
    for (int r = 0; r < 16; ++r) {
        const int qrow = (r & 3) + 8 * (r >> 2) + 4 * hi2;
        const float s  = __shfl(psum, qrow);
        const float rs = 1.0f / s;
        #pragma unroll
        for (int dt = 0; dt < 4; ++dt) {
            obase[(size_t)qrow * DD + 32 * dt] = oacc[dt][r] * rs;
        }
    }
}

extern "C" void kernel_launch(void* const* d_in, const int* in_sizes, int n_in,
                              void* d_out, int out_size, void* d_ws, size_t ws_size,
                              hipStream_t stream)
{
    const float* q = (const float*)d_in[0];
    const float* k = (const float*)d_in[1];
    const float* v = (const float*)d_in[2];
    const void*  m = d_in[3];
    float*       o = (float*)d_out;
    hipLaunchKernelGGL(attn_fwd, dim3((NB * SLQ) / QTILE), dim3(512), 0, stream,
                       q, k, v, m, o);
}

// Round 14
// 255.048 us; speedup vs baseline: 8.3860x; 1.3535x over previous
//
#include <hip/hip_runtime.h>
#include <stdint.h>

// Problem constants (B, LQ, LK, D fixed by the reference)
#define NB    32
#define SLQ   2048
#define SLK   2048
#define DD    128
#define QTILE 128          // q rows per workgroup (4 waves x 32)
#define KVB   64           // keys per block iteration
#define NKB   (SLK / KVB)  // 32
#define TILEB 16384        // bytes per K or V^T bf16 tile image (64x128x2)

typedef __attribute__((ext_vector_type(8)))  short    bf16x8;
typedef __attribute__((ext_vector_type(16))) float    f32x16;
typedef __attribute__((ext_vector_type(4)))  float    f32x4v;
typedef __attribute__((ext_vector_type(4)))  uint32_t u32x4;
typedef __attribute__((ext_vector_type(2)))  uint32_t u32x2;

union FragU { uint32_t u[4]; bf16x8 v; };

__device__ __forceinline__ uint32_t cvtpk(float lo, float hi) {
    uint32_t r;
    asm("v_cvt_pk_bf16_f32 %0, %1, %2" : "=v"(r) : "v"(lo), "v"(hi));
    return r;
}
__device__ __forceinline__ void perm32swap(uint32_t& a, uint32_t& b) {
    asm("v_permlane32_swap_b32 %0, %1" : "+v"(a), "+v"(b));
}
__device__ __forceinline__ uint32_t pack16(u32x4 a) {
    uint32_t r0 = (((a.x & 0x01010101u) * 0x01020408u) >> 24) & 0xFu;
    uint32_t r1 = (((a.y & 0x01010101u) * 0x01020408u) >> 24) & 0xFu;
    uint32_t r2 = (((a.z & 0x01010101u) * 0x01020408u) >> 24) & 0xFu;
    uint32_t r3 = (((a.w & 0x01010101u) * 0x01020408u) >> 24) & 0xFu;
    return r0 | (r1 << 4) | (r2 << 8) | (r3 << 12);
}
#if __has_builtin(__builtin_amdgcn_exp2f)
#define EXP2(x) __builtin_amdgcn_exp2f(x)
#else
#define EXP2(x) exp2f(x)
#endif

// ---------------------------------------------------------------------------
// prep_k: K f32 -> bf16 tile images with QK^T XOR-swizzle PRE-APPLIED so the
// main kernel's global_load_lds fills LDS linearly (m173 / rule #21 pattern).
// image[tile][kk*256 + ((8c) ^ ((kk&7)<<4))] = bf16(K[kk][4c..4c+3])
// ---------------------------------------------------------------------------
__global__ __launch_bounds__(256, 8)
void prep_k(const float* __restrict__ kp, char* __restrict__ kimg)
{
    const int t  = blockIdx.x * 256 + threadIdx.x;   // 2,097,152 total
    const int c  = t & 31;           // 8B chunk (d = 4c..4c+3)
    const int kk = (t >> 5) & 63;    // key row in tile
    const int kb = (t >> 11) & 31;   // tile
    const int b  = t >> 16;          // batch
    const float* src = kp + ((size_t)b * SLK + (size_t)(kb * KVB + kk)) * DD + 4 * c;
    f32x4v x = *(const f32x4v*)src;
    u32x2 w; w.x = cvtpk(x.x, x.y); w.y = cvtpk(x.z, x.w);
    char* dst = kimg + (size_t)(b * NKB + kb) * TILEB + kk * 256 + ((8 * c) ^ ((kk & 7) << 4));
    *(u32x2*)dst = w;
}

// ---------------------------------------------------------------------------
// prep_v: V f32 -> transposed V^T bf16 tile images, PV XOR-swizzle pre-applied.
// image[tile][d*128 + ((8c) ^ ((d&15)<<3))] = bf16(V[4c..4c+3][d])
// ---------------------------------------------------------------------------
__global__ __launch_bounds__(256, 8)
void prep_v(const float* __restrict__ vp, char* __restrict__ vimg)
{
    const int t  = blockIdx.x * 256 + threadIdx.x;   // 2,097,152 total
    const int d  = t & 127;          // d row of V^T
    const int c  = (t >> 7) & 15;    // 8B chunk (keys 4c..4c+3)
    const int kb = (t >> 11) & 31;   // tile
    const int b  = t >> 16;          // batch
    const float* src = vp + ((size_t)b * SLK + (size_t)(kb * KVB + 4 * c)) * DD + d;
    const float a0 = src[0], a1 = src[DD], a2 = src[2 * DD], a3 = src[3 * DD];
    u32x2 w; w.x = cvtpk(a0, a1); w.y = cvtpk(a2, a3);
    char* dst = vimg + (size_t)(b * NKB + kb) * TILEB + d * 128 + ((8 * c) ^ ((d & 15) << 3));
    *(u32x2*)dst = w;
}

// ---------------------------------------------------------------------------
// prep_m: bool mask -> 1 bit/key, [b][q][256B row]. Kills the 64B-granule
// scatter (134MB -> 16.8MB) and all per-iter pack VALU in the main kernel.
// ---------------------------------------------------------------------------
__global__ __launch_bounds__(256, 8)
void prep_m(const void* __restrict__ mp, uint32_t* __restrict__ mbits)
{
    __shared__ int det_flags;
    if (threadIdx.x == 0) det_flags = 0;
    __syncthreads();
    {
        const u32x4 w = *(const u32x4*)((const char*)mp + threadIdx.x * 16);
        const uint32_t any_hi    = (w.x | w.y | w.z | w.w) & 0xFFFFFF00u;
        const uint32_t any_mod84 = (w.y | w.w) & 0xFFu;
        const int f = (any_hi ? 1 : 0) | (any_mod84 ? 2 : 0);
        if (f) atomicOr(&det_flags, f);
    }
    __syncthreads();
    const int mflags = det_flags;
    const int mmode  = (mflags & 1) ? 0 : ((mflags & 2) ? 1 : 2);  // 0=u8,1=i32,2=i64

    const int t   = blockIdx.x * 256 + threadIdx.x;  // 4,194,304 total
    const int k32 = t & 63;          // 32-key group
    const int q   = (t >> 6) & 2047;
    const int b   = t >> 17;
    const size_t e0 = ((size_t)b * SLQ + q) * SLK + (size_t)k32 * 32;
    uint32_t bits;
    if (mmode == 0) {
        const uint8_t* src = (const uint8_t*)mp + e0;
        u32x4 a = *(const u32x4*)(src);
        u32x4 c = *(const u32x4*)(src + 16);
        bits = pack16(a) | (pack16(c) << 16);
    } else if (mmode == 1) {
        const uint32_t* s = (const uint32_t*)mp + e0;
        bits = 0;
        for (int j = 0; j < 32; ++j) bits |= (s[j] ? 1u : 0u) << j;
    } else {
        const uint64_t* s = (const uint64_t*)mp + e0;
        bits = 0;
        for (int j = 0; j < 32; ++j) bits |= (s[j] ? 1u : 0u) << j;
    }
    mbits[((size_t)b * SLQ + q) * 64 + k32] = bits;
}

// ---------------------------------------------------------------------------
// Main kernel: R5 compute math, staging via global_load_lds from pre-swizzled
// bf16 images. Double-buffered LDS, 1 vmcnt(0) + 1 barrier per iteration.
// Zero staging registers, zero staging VALU.
// ---------------------------------------------------------------------------
__global__ __launch_bounds__(256, 2)
void attn_main(const float* __restrict__ qp, const char* __restrict__ kimg,
               const char* __restrict__ vimg, const uint32_t* __restrict__ mbits,
               float* __restrict__ op)
{
    __shared__ short k_lds[2][KVB * DD];    // 2 x 16KB, image order (pre-swizzled)
    __shared__ short vt_lds[2][DD * KVB];   // 2 x 16KB

    const int tid  = threadIdx.x;
    const int lane = tid & 63;
    const int wv   = tid >> 6;   // wave 0..3
    const int l31  = lane & 31;
    const int hi2  = lane >> 5;  // 0/1

    // XCD-chunked swizzle: 512 WGs, 8 XCDs -> 64 consecutive work ids each
    const int bid = blockIdx.x;
    const int wg  = (bid & 7) * 64 + (bid >> 3);
    const int b   = wg >> 4;            // batch
    const int q0  = (wg & 15) * QTILE;  // q tile origin

    // scale = log2(e)/sqrt(128): scores in log2 units -> softmax is bare v_exp
    const float qsc = 0.12751744846458246f;

    // ---- persistent Q fragments (B-operand of swapped QK^T), from f32 ----
    bf16x8 qf[8];
    {
        const float* qrow = qp + ((size_t)b * SLQ + (size_t)(q0 + wv * 32 + l31)) * DD;
        #pragma unroll
        for (int ks = 0; ks < 8; ++ks) {
            f32x4v x0 = *(const f32x4v*)(qrow + 16 * ks + 8 * hi2);
            f32x4v x1 = *(const f32x4v*)(qrow + 16 * ks + 8 * hi2 + 4);
            FragU f;
            f.u[0] = cvtpk(x0.x * qsc, x0.y * qsc);
            f.u[1] = cvtpk(x0.z * qsc, x0.w * qsc);
            f.u[2] = cvtpk(x1.x * qsc, x1.y * qsc);
            f.u[3] = cvtpk(x1.z * qsc, x1.w * qsc);
            qf[ks] = f.v;
        }
    }

    f32x16 oacc[4];
    #pragma unroll
    for (int i = 0; i < 4; ++i)
        #pragma unroll
        for (int j = 0; j < 16; ++j) oacc[i][j] = 0.0f;
    float psum = 0.0f;

    const char* ktb = kimg + (size_t)b * NKB * TILEB;
    const char* vtb = vimg + (size_t)b * NKB * TILEB;
    const uint32_t* mrow = mbits + ((size_t)b * SLQ + (size_t)(q0 + 32 * wv + l31)) * 64;

    // Each wave DMA-fills its 4KB slice of each tile: 4x1KB K + 4x1KB V.
    #define ISSUE(T, BUF)                                                         \
        do {                                                                      \
            const char* ksrc_ = ktb + (size_t)(T) * TILEB;                        \
            const char* vsrc_ = vtb + (size_t)(T) * TILEB;                        \
            _Pragma("unroll")                                                     \
            for (int j = 0; j < 4; ++j) {                                         \
                const int ci = wv * 4 + j;                                        \
                __builtin_amdgcn_global_load_lds(                                 \
                    (const uint32_t*)(ksrc_ + ci * 1024 + lane * 16),             \
                    (uint32_t*)((char*)k_lds[(BUF)] + ci * 1024), 16, 0, 0);      \
                __builtin_amdgcn_global_load_lds(                                 \
                    (const uint32_t*)(vsrc_ + ci * 1024 + lane * 16),             \
                    (uint32_t*)((char*)vt_lds[(BUF)] + ci * 1024), 16, 0, 0);     \
            }                                                                     \
        } while (0)

    ISSUE(0, 0);

    for (int kb = 0; kb < NKB; ++kb) {
        const int cur = kb & 1;

        // tile kb resident after this wave's own DMAs drain + barrier
        asm volatile("s_waitcnt vmcnt(0)" ::: "memory");
        __syncthreads();
        if (kb + 1 < NKB) ISSUE(kb + 1, cur ^ 1);
        __builtin_amdgcn_sched_barrier(0);

        // mask bits for this lane's q-row, 64 keys (L2-resident 8B load)
        const u32x2 mq = *(const u32x2*)(mrow + kb * 2);

        const short* kl = k_lds[cur];
        const short* vl = vt_lds[cur];

        // ---- swapped QK^T: sacc[t] = S^T (keys 32t.. x 32 q), log2 units ----
        f32x16 sacc[2];
        #pragma unroll
        for (int t = 0; t < 2; ++t)
            #pragma unroll
            for (int j = 0; j < 16; ++j) sacc[t][j] = 0.0f;
        __builtin_amdgcn_s_setprio(1);
        #pragma unroll
        for (int t = 0; t < 2; ++t) {
            const int row = 32 * t + l31;
            const char* krow = (const char*)kl + row * 256;
            const int sw = (row & 7) << 4;
            #pragma unroll
            for (int ks = 0; ks < 8; ++ks) {
                bf16x8 af = *(const bf16x8*)(krow + ((32 * ks + 16 * hi2) ^ sw));
                sacc[t] = __builtin_amdgcn_mfma_f32_32x32x16_bf16(af, qf[ks], sacc[t], 0, 0, 0);
            }
        }
        __builtin_amdgcn_s_setprio(0);

        // ---- softmax: p = exp2(s'), mask via bits, f32 row-sum, pack bf16 ----
        uint32_t pw[2][8];
        #pragma unroll
        for (int t = 0; t < 2; ++t) {
            #pragma unroll
            for (int rr = 0; rr < 4; ++rr) {
                const uint32_t mn = ((t ? mq.y : mq.x) >> (8 * rr + 4 * hi2)) & 0xFu;
                float em[4];
                #pragma unroll
                for (int c = 0; c < 4; ++c) {
                    const float e = EXP2(sacc[t][4 * rr + c]);
                    em[c] = ((mn >> c) & 1u) ? 0.0f : e;
                }
                psum += (em[0] + em[1]) + (em[2] + em[3]);
                pw[t][2 * rr]     = cvtpk(em[0], em[1]);
                pw[t][2 * rr + 1] = cvtpk(em[2], em[3]);
            }
        }

        // ---- PV: O[32q x 128d] += P[32x64] * V[64x128] ----
        #pragma unroll
        for (int t = 0; t < 2; ++t) {
            #pragma unroll
            for (int kss = 0; kss < 2; ++kss) {
                uint32_t a0 = pw[t][4 * kss + 0], b0 = pw[t][4 * kss + 2];
                uint32_t a1 = pw[t][4 * kss + 1], b1 = pw[t][4 * kss + 3];
                perm32swap(a0, b0);
                perm32swap(a1, b1);
                FragU af;
                af.u[0] = a0; af.u[1] = a1; af.u[2] = b0; af.u[3] = b1;
                const int keyb = 64 * t + 32 * kss + 16 * hi2;
                __builtin_amdgcn_s_setprio(1);
                #pragma unroll
                for (int dt = 0; dt < 4; ++dt) {
                    const int drow = 32 * dt + l31;
                    const char* vrow = (const char*)vl + drow * 128;
                    const int sw8 = (drow & 15) << 3;
                    FragU vf;
                    *(u32x2*)&vf.u[0] = *(const u32x2*)(vrow + ((keyb)     ^ sw8));
                    *(u32x2*)&vf.u[2] = *(const u32x2*)(vrow + ((keyb + 8) ^ sw8));
                    oacc[dt] = __builtin_amdgcn_mfma_f32_32x32x16_bf16(af.v, vf.v, oacc[dt], 0, 0, 0);
                }
                __builtin_amdgcn_s_setprio(0);
            }
        }
        // no trailing barrier: next iter's vmcnt+barrier provides the sync
    }

    // ---- epilogue: combine halves of row-sums, normalize, store fp32 ----
    psum += __shfl_xor(psum, 32);
    float* obase = op + ((size_t)b * SLQ + (size_t)(q0 + 32 * wv)) * DD + l31;
    #pragma unroll
    for (int r = 0; r < 16; ++r) {
        const int qrow = (r & 3) + 8 * (r >> 2) + 4 * hi2;
        const float s  = __shfl(psum, qrow);
        const float rs = 1.0f / s;
        #pragma unroll
        for (int dt = 0; dt < 4; ++dt) {
            obase[(size_t)qrow * DD + 32 * dt] = oacc[dt][r] * rs;
        }
    }
}

extern "C" void kernel_launch(void* const* d_in, const int* in_sizes, int n_in,
                              void* d_out, int out_size, void* d_ws, size_t ws_size,
                              hipStream_t stream)
{
    const float* q = (const float*)d_in[0];
    const float* k = (const float*)d_in[1];
    const float* v = (const float*)d_in[2];
    const void*  m = d_in[3];
    float*       o = (float*)d_out;

    char*     kimg  = (char*)d_ws;                        // 16.78 MB
    char*     vimg  = kimg + (size_t)NB * NKB * TILEB;    // 16.78 MB
    uint32_t* mbits = (uint32_t*)(vimg + (size_t)NB * NKB * TILEB);  // 16.78 MB

    hipLaunchKernelGGL(prep_k, dim3(8192),  dim3(256), 0, stream, k, kimg);
    hipLaunchKernelGGL(prep_v, dim3(8192),  dim3(256), 0, stream, v, vimg);
    hipLaunchKernelGGL(prep_m, dim3(16384), dim3(256), 0, stream, m, mbits);
    hipLaunchKernelGGL(attn_main, dim3((NB * SLQ) / QTILE), dim3(256), 0, stream,
                       q, kimg, vimg, mbits, o);
}